// Round 3
// baseline (134.727 us; speedup 1.0000x reference)
//
#include <hip/hip_runtime.h>

#define MT    132      // padded (M+1): 129 valid + 3 zero pad
#define NSEQ  512
#define LSEQ  256
#define MM    128      // M
#define NROW  129      // M+1
#define BETA  10.0     // reweighting: track a * e^{BETA*(t - mp)}
#define LOG2E 1.4426950408889634
#define LN2   0.6931471805599453

// per-mp transition tables (indexed by i = chain/source index), REWEIGHTED
enum { T_TMX=0, T_TIX, T_TMEQ0, T_TIEQ0, T_TMEQ1, T_TIEQ1,
       T_ENT0, T_ENT1, T_STP, T_I0, T_I1, T_COUNT };          // 11

#define TOK_BYTES (NSEQ*LSEQ)            // 131072 (uint8 tokens)
#define TABD_OFF  TOK_BYTES              // doubles, 8-aligned
#define TABD_CNT  (T_COUNT*MT)           // 1452 doubles
#define EMF_OFF   (TABD_OFF + TABD_CNT*8)
#define EMF_CNT   (2*25*MT)              // 6600 floats
#define EI_REL    (25*MT)                // 3300

__device__ __forceinline__ double lse2d(double a, double b) {
  double m = fmax(a, b);
  return m + log(exp(a - m) + exp(b - m));
}

// ---------------------------------------------------------------- prep ----
__global__ void prep_kernel(const float* __restrict__ anc,
                            const float* __restrict__ insq,
                            const float* __restrict__ rr,
                            const float* __restrict__ uu,
                            double* __restrict__ tabd,
                            float* __restrict__ emf) {
  __shared__ double ls[T_COUNT*MT];
  const int tid = threadIdx.x;

  if (tid < MT) {
    double v[T_COUNT];
#pragma unroll
    for (int k = 0; k < T_COUNT; ++k) v[k] = 0.0;
    if (tid <= MM) {
      const int m = tid;
      double rn[3][2], un[3][2];
#pragma unroll
      for (int j = 0; j < 3; ++j) {
        double a0 = (double)rr[(m*3+j)*2+0], a1 = (double)rr[(m*3+j)*2+1];
        double l  = lse2d(a0, a1);
        rn[j][0] = a0 - l; rn[j][1] = a1 - l;
        double b0 = (double)uu[(m*3+j)*2+0], b1 = (double)uu[(m*3+j)*2+1];
        double l2 = lse2d(b0, b1);
        un[j][0] = b0 - l2; un[j][1] = b1 - l2;
      }
      v[T_TMX]   = exp(rn[0][0] + un[0][1] - BETA);  // match exit -> chain  (x e^-B)
      v[T_TIX]   = exp(rn[1][0] + un[1][1]);         // insert exit -> chain
      v[T_TMEQ0] = exp(rn[0][0] + un[0][0]);         // match -> (i,0)
      v[T_TIEQ0] = exp(rn[1][0] + un[1][0] + BETA);  // insert -> (i,0)      (x e^+B)
      v[T_TMEQ1] = exp(rn[0][1]);                    // match -> (i,1)
      v[T_TIEQ1] = exp(rn[1][1] + BETA);             // insert -> (i,1)      (x e^+B)
      v[T_ENT0]  = exp(rn[2][0] + un[2][0]);         // chain -> (mp,0)
      v[T_ENT1]  = exp(rn[2][1]);                    // chain -> (mp,1)
      v[T_STP]   = exp(rn[2][0] + un[2][1] - BETA);  // chain continue       (x e^-B)
    }
#pragma unroll
    for (int k = 0; k < T_COUNT; ++k) ls[k*MT + tid] = v[k];
  }
  __syncthreads();

  if (tid == 0) {   // initial dist (virtual source i=0,j=0), reweighted tables
    ls[T_I0*MT+0] = ls[T_TMEQ0*MT+0];
    ls[T_I1*MT+0] = ls[T_TMEQ1*MT+0];
    double c = ls[T_TMX*MT+0];
    for (int mp = 1; mp <= MM; ++mp) {
      ls[T_I0*MT+mp] = c * ls[T_ENT0*MT+mp];
      ls[T_I1*MT+mp] = c * ls[T_ENT1*MT+mp];
      c *= ls[T_STP*MT+mp];
    }
  }
  __syncthreads();

  for (int i = tid; i < T_COUNT*MT; i += blockDim.x) tabd[i] = ls[i];

  // emission tables: EM_T[d][m] = softmax(anc[m])[d] (transposed), d<24
  for (int row = tid; row < 2*NROW; row += blockDim.x) {
    const bool isM = row < NROW;
    const int  m   = isM ? row : row - NROW;
    const float* src = (isM ? anc : insq) + m*24;
    float* dst = emf + (isM ? 0 : EI_REL);
    float mx = -1e30f;
    for (int d = 0; d < 24; ++d) mx = fmaxf(mx, src[d]);
    float s = 0.f;
    for (int d = 0; d < 24; ++d) s += __expf(src[d] - mx);
    float is = 1.f / s;
    for (int d = 0; d < 24; ++d) dst[d*MT + m] = __expf(src[d] - mx) * is;
  }
  // masked-token row (tok==24) = 1.0 on valid cols, 0 on pads
  for (int i = tid; i < MT; i += blockDim.x) {
    float v = (i <= MM) ? 1.f : 0.f;
    emf[         24*MT + i] = v;
    emf[EI_REL + 24*MT + i] = v;
  }
  // zero pad cols (129..131) of token rows d<24, both tables
  for (int i = tid; i < 2*24*3; i += blockDim.x) {
    int which = i / 72, rem = i % 72, d = rem / 3, c = NROW + rem % 3;
    emf[which*EI_REL + d*MT + c] = 0.f;
  }
}

// ---------------------------------------------------------------- tok -----
__global__ void tok_kernel(const float* __restrict__ data,
                           unsigned char* __restrict__ toks) {
  const int t = threadIdx.x;
  const int n = blockIdx.x;
  const float* p = data + (size_t)(n*LSEQ + t)*24;
  int tok = 24;
#pragma unroll
  for (int d = 0; d < 24; ++d) if (p[d] > 0.5f) tok = d;
  toks[n*LSEQ + t] = (unsigned char)tok;
}

// ---------------------------------------------------------------- fwd -----
__global__ __launch_bounds__(64)
void fwd_kernel(const double* __restrict__ tabd,
                const float* __restrict__ emf,
                const unsigned char* __restrict__ toks,
                float* __restrict__ out) {
  __shared__ float ldsE[EMF_CNT];
  __shared__ int   ldsT[LSEQ];
  const int lane = threadIdx.x;
  const int n    = blockIdx.x;

  for (int i = lane; i < EMF_CNT; i += 64) ldsE[i] = emf[i];
  const unsigned char* tp = toks + n*LSEQ;
  for (int i = lane; i < LSEQ; i += 64) ldsT[i] = (int)tp[i] * MT;

  const int mp0 = 3*lane;
  double tmx[3], tix[3], te0m[3], te0i[3], te1m[3], te1i[3],
         en0[3], en1[3], stp[3], i0v[3], i1v[3];
  int col[3];
#pragma unroll
  for (int j = 0; j < 3; ++j) {
    int mp = mp0 + j;
    bool ok = mp < MT;
    col[j] = ok ? mp : (MT-1);
    int ix = ok ? mp : 0;
    tmx[j]  = ok ? tabd[T_TMX  *MT+ix] : 0.0;
    tix[j]  = ok ? tabd[T_TIX  *MT+ix] : 0.0;
    te0m[j] = ok ? tabd[T_TMEQ0*MT+ix] : 0.0;
    te0i[j] = ok ? tabd[T_TIEQ0*MT+ix] : 0.0;
    te1m[j] = ok ? tabd[T_TMEQ1*MT+ix] : 0.0;
    te1i[j] = ok ? tabd[T_TIEQ1*MT+ix] : 0.0;
    en0[j]  = ok ? tabd[T_ENT0 *MT+ix] : 0.0;
    en1[j]  = ok ? tabd[T_ENT1 *MT+ix] : 0.0;
    stp[j]  = ok ? tabd[T_STP  *MT+ix] : 0.0;
    i0v[j]  = ok ? tabd[T_I0   *MT+ix] : 0.0;
    i1v[j]  = ok ? tabd[T_I1   *MT+ix] : 0.0;
  }
  const double s2v = stp[2];
  const double s12 = stp[1]*stp[2];

  // loop-invariant multiplier windows for the cross-lane affine scan
  double Sr[6];
  {
    double S = stp[0]*s12;
#pragma unroll
    for (int r = 0; r < 6; ++r) {
      int d = 1 << r;
      Sr[r] = S;
      double sf = __shfl_up(S, d);
      if (lane < d) sf = 1.0;
      S = sf * S;
    }
  }
  __syncthreads();

  // initial alpha (reweighted linear domain, fp64)
  double aM[3], aI[3];
  {
    int t0 = ldsT[0];
#pragma unroll
    for (int j = 0; j < 3; ++j) {
      aM[j] = i0v[j] * (double)ldsE[t0 + col[j]];
      aI[j] = i1v[j] * (double)ldsE[EI_REL + t0 + col[j]];
    }
  }
  double acc2 = 0.0;   // accumulated log2 of removed power-of-2 factors

  for (int t = 1; t < LSEQ; ++t) {
    const int toff = ldsT[t];
    double ap0 = __shfl_up(aM[2], 1);
    if (lane == 0) ap0 = 0.0;
    double ap[3] = {ap0, aM[0], aM[1]};
    double X[3], e0[3], e1[3];
#pragma unroll
    for (int j = 0; j < 3; ++j) {
      X[j]  = fma(ap[j], tmx[j],  aI[j]*tix[j]);   // feeds delete chain
      e0[j] = fma(ap[j], te0m[j], aI[j]*te0i[j]);  // direct -> (mp,0)
      e1[j] = fma(ap[j], te1m[j], aI[j]*te1i[j]);  // direct -> (mp,1)
    }
    // local composite, then 6-round cross-lane affine scan
    double x = fma(X[0], s12, fma(X[1], s2v, X[2]));
#pragma unroll
    for (int r = 0; r < 6; ++r) {
      int d = 1 << r;
      double xf = __shfl_up(x, d);
      if (lane < d) xf = 0.0;
      x = fma(xf, Sr[r], x);
    }
    double C0 = __shfl_up(x, 1);
    if (lane == 0) C0 = 0.0;
    double C1 = fma(C0, stp[0], X[0]);
    double C2 = fma(C1, stp[1], X[1]);
    double Cv[3] = {C0, C1, C2};
#pragma unroll
    for (int j = 0; j < 3; ++j) {
      double b0 = fma(en0[j], Cv[j], e0[j]);
      double b1 = fma(en1[j], Cv[j], e1[j]);
      aM[j] = b0 * (double)ldsE[toff + col[j]];
      aI[j] = b1 * (double)ldsE[EI_REL + toff + col[j]];
    }
    // exact exponent-only renorm every 8 steps (power-of-2: no rounding)
    if ((t & 7) == 0) {
      double mx = fmax(fmax(fmax(aM[0],aM[1]), fmax(aM[2],aI[0])),
                       fmax(aI[1],aI[2]));
#pragma unroll
      for (int r = 0; r < 6; ++r) mx = fmax(mx, __shfl_xor(mx, 1 << r));
      mx = fmax(mx, 1e-300);
      int e = ilogb(mx);
      double sc = ldexp(1.0, -e);
      acc2 += (double)e;
#pragma unroll
      for (int j = 0; j < 3; ++j) { aM[j] *= sc; aI[j] *= sc; }
    }
  }

  // final: undo reweighting per state (log2 a = log2 a~ + B*log2e*mp + acc2)
  double l2[6];
#pragma unroll
  for (int j = 0; j < 3; ++j) {
    double vm = aM[j], vi = aI[j];
    double w = BETA * LOG2E * (double)(mp0 + j);
    l2[j]   = (vm > 0.0 ? log2(vm) + w : -1.0e300);
    l2[3+j] = (vi > 0.0 ? log2(vi) + w : -1.0e300);
  }
  double lm = l2[0];
#pragma unroll
  for (int j = 1; j < 6; ++j) lm = fmax(lm, l2[j]);
#pragma unroll
  for (int r = 0; r < 6; ++r) lm = fmax(lm, __shfl_xor(lm, 1 << r));
  lm = fmax(lm, -1.0e280);
  double s = 0.0;
#pragma unroll
  for (int j = 0; j < 6; ++j) s += exp2(l2[j] - lm);
#pragma unroll
  for (int r = 0; r < 6; ++r) s += __shfl_xor(s, 1 << r);
  if (lane == 0) {
    // correction: -255*BETA nats (e^{B t} reweight at t=255)
    out[n] = (float)(LN2*(lm + acc2 + log2(s)) - 255.0*BETA);
  }
}

// ---------------------------------------------------------------- launch --
extern "C" void kernel_launch(void* const* d_in, const int* in_sizes, int n_in,
                              void* d_out, int out_size, void* d_ws, size_t ws_size,
                              hipStream_t stream) {
  const float* anc  = (const float*)d_in[0];
  const float* insq = (const float*)d_in[1];
  const float* rr   = (const float*)d_in[2];
  const float* uu   = (const float*)d_in[3];
  const float* data = (const float*)d_in[4];
  float* out = (float*)d_out;

  unsigned char* toks = (unsigned char*)d_ws;
  double* tabd = (double*)((char*)d_ws + TABD_OFF);
  float*  emf  = (float*) ((char*)d_ws + EMF_OFF);

  hipLaunchKernelGGL(prep_kernel, dim3(1),    dim3(256), 0, stream,
                     anc, insq, rr, uu, tabd, emf);
  hipLaunchKernelGGL(tok_kernel,  dim3(NSEQ), dim3(LSEQ), 0, stream, data, toks);
  hipLaunchKernelGGL(fwd_kernel,  dim3(NSEQ), dim3(64),  0, stream,
                     tabd, emf, toks, out);
}

// Round 4
// 87.154 us; speedup vs baseline: 1.5459x; 1.5459x over previous
//
#include <hip/hip_runtime.h>

#define MT    132      // padded (M+1): 129 valid + 3 zero pad
#define NSEQ  512
#define LSEQ  256
#define MM    128      // M
#define NROW  129      // M+1
#define BETA  10.0     // reweighting: track a * e^{BETA*(t - mp)}
#define LOG2E 1.4426950408889634
#define LN2   0.6931471805599453

// per-mp transition tables (indexed by i = chain/source index), REWEIGHTED
enum { T_TMX=0, T_TIX, T_TMEQ0, T_TIEQ0, T_TMEQ1, T_TIEQ1,
       T_ENT0, T_ENT1, T_STP, T_I0, T_I1, T_COUNT };          // 11

#define TOK_BYTES (NSEQ*LSEQ)            // 131072 (uint8 tokens)
#define TABD_OFF  TOK_BYTES              // doubles, 8-aligned
#define TABD_CNT  (T_COUNT*MT)           // 1452 doubles
#define EMF_OFF   (TABD_OFF + TABD_CNT*8)
#define EMF_CNT   (2*25*MT)              // 6600 floats
#define EI_REL    (25*MT)                // 3300

// DPP ctrl encodings (gfx9/CDNA): ROW_SHR:d = 0x110+d, WAVE_SHR1 = 0x138,
// ROW_BCAST15 = 0x142, ROW_BCAST31 = 0x143.
template <int CTRL, int RMASK, bool BC>
__device__ __forceinline__ double dpp_d(double v) {
  int lo = __double2loint(v), hi = __double2hiint(v);
  lo = __builtin_amdgcn_update_dpp(0, lo, CTRL, RMASK, 0xF, BC);
  hi = __builtin_amdgcn_update_dpp(0, hi, CTRL, RMASK, 0xF, BC);
  return __hiloint2double(hi, lo);
}

__device__ __forceinline__ double lse2d(double a, double b) {
  double m = fmax(a, b);
  return m + log(exp(a - m) + exp(b - m));
}

// ---------------------------------------------------------------- prep ----
__global__ void prep_kernel(const float* __restrict__ anc,
                            const float* __restrict__ insq,
                            const float* __restrict__ rr,
                            const float* __restrict__ uu,
                            double* __restrict__ tabd,
                            float* __restrict__ emf) {
  __shared__ double ls[T_COUNT*MT];
  const int tid = threadIdx.x;

  if (tid < MT) {
    double v[T_COUNT];
#pragma unroll
    for (int k = 0; k < T_COUNT; ++k) v[k] = 0.0;
    if (tid <= MM) {
      const int m = tid;
      double rn[3][2], un[3][2];
#pragma unroll
      for (int j = 0; j < 3; ++j) {
        double a0 = (double)rr[(m*3+j)*2+0], a1 = (double)rr[(m*3+j)*2+1];
        double l  = lse2d(a0, a1);
        rn[j][0] = a0 - l; rn[j][1] = a1 - l;
        double b0 = (double)uu[(m*3+j)*2+0], b1 = (double)uu[(m*3+j)*2+1];
        double l2 = lse2d(b0, b1);
        un[j][0] = b0 - l2; un[j][1] = b1 - l2;
      }
      v[T_TMX]   = exp(rn[0][0] + un[0][1] - BETA);  // match exit -> chain  (x e^-B)
      v[T_TIX]   = exp(rn[1][0] + un[1][1]);         // insert exit -> chain
      v[T_TMEQ0] = exp(rn[0][0] + un[0][0]);         // match -> (i,0)
      v[T_TIEQ0] = exp(rn[1][0] + un[1][0] + BETA);  // insert -> (i,0)      (x e^+B)
      v[T_TMEQ1] = exp(rn[0][1]);                    // match -> (i,1)
      v[T_TIEQ1] = exp(rn[1][1] + BETA);             // insert -> (i,1)      (x e^+B)
      v[T_ENT0]  = exp(rn[2][0] + un[2][0]);         // chain -> (mp,0)
      v[T_ENT1]  = exp(rn[2][1]);                    // chain -> (mp,1)
      v[T_STP]   = exp(rn[2][0] + un[2][1] - BETA);  // chain continue       (x e^-B)
    }
#pragma unroll
    for (int k = 0; k < T_COUNT; ++k) ls[k*MT + tid] = v[k];
  }
  __syncthreads();

  if (tid == 0) {   // initial dist (virtual source i=0,j=0), reweighted tables
    ls[T_I0*MT+0] = ls[T_TMEQ0*MT+0];
    ls[T_I1*MT+0] = ls[T_TMEQ1*MT+0];
    double c = ls[T_TMX*MT+0];
    for (int mp = 1; mp <= MM; ++mp) {
      ls[T_I0*MT+mp] = c * ls[T_ENT0*MT+mp];
      ls[T_I1*MT+mp] = c * ls[T_ENT1*MT+mp];
      c *= ls[T_STP*MT+mp];
    }
  }
  __syncthreads();

  for (int i = tid; i < T_COUNT*MT; i += blockDim.x) tabd[i] = ls[i];

  // emission tables: EM_T[d][m] = softmax(anc[m])[d] (transposed), d<24
  for (int row = tid; row < 2*NROW; row += blockDim.x) {
    const bool isM = row < NROW;
    const int  m   = isM ? row : row - NROW;
    const float* src = (isM ? anc : insq) + m*24;
    float* dst = emf + (isM ? 0 : EI_REL);
    float mx = -1e30f;
    for (int d = 0; d < 24; ++d) mx = fmaxf(mx, src[d]);
    float s = 0.f;
    for (int d = 0; d < 24; ++d) s += __expf(src[d] - mx);
    float is = 1.f / s;
    for (int d = 0; d < 24; ++d) dst[d*MT + m] = __expf(src[d] - mx) * is;
  }
  // masked-token row (tok==24) = 1.0 on valid cols, 0 on pads
  for (int i = tid; i < MT; i += blockDim.x) {
    float v = (i <= MM) ? 1.f : 0.f;
    emf[         24*MT + i] = v;
    emf[EI_REL + 24*MT + i] = v;
  }
  // zero pad cols (129..131) of token rows d<24, both tables
  for (int i = tid; i < 2*24*3; i += blockDim.x) {
    int which = i / 72, rem = i % 72, d = rem / 3, c = NROW + rem % 3;
    emf[which*EI_REL + d*MT + c] = 0.f;
  }
}

// ---------------------------------------------------------------- tok -----
__global__ void tok_kernel(const float* __restrict__ data,
                           unsigned char* __restrict__ toks) {
  const int t = threadIdx.x;
  const int n = blockIdx.x;
  const float* p = data + (size_t)(n*LSEQ + t)*24;
  int tok = 24;
#pragma unroll
  for (int d = 0; d < 24; ++d) if (p[d] > 0.5f) tok = d;
  toks[n*LSEQ + t] = (unsigned char)tok;
}

// ---------------------------------------------------------------- fwd -----
__global__ __launch_bounds__(64)
void fwd_kernel(const double* __restrict__ tabd,
                const float* __restrict__ emf,
                const unsigned char* __restrict__ toks,
                float* __restrict__ out) {
  __shared__ float ldsE[EMF_CNT];
  __shared__ int   ldsT[LSEQ];
  const int lane = threadIdx.x;
  const int n    = blockIdx.x;

  for (int i = lane; i < EMF_CNT; i += 64) ldsE[i] = emf[i];
  const unsigned char* tp = toks + n*LSEQ;
  for (int i = lane; i < LSEQ; i += 64) ldsT[i] = (int)tp[i] * MT;

  const int mp0 = 3*lane;
  double tmx[3], tix[3], te0m[3], te0i[3], te1m[3], te1i[3],
         en0[3], en1[3], stpd[3], i0v[3], i1v[3];
  int col[3];
#pragma unroll
  for (int j = 0; j < 3; ++j) {
    int mp = mp0 + j;
    bool ok = mp < MT;
    col[j] = ok ? mp : (MT-1);
    int ix = ok ? mp : 0;
    tmx[j]  = ok ? tabd[T_TMX  *MT+ix] : 0.0;
    tix[j]  = ok ? tabd[T_TIX  *MT+ix] : 0.0;
    te0m[j] = ok ? tabd[T_TMEQ0*MT+ix] : 0.0;
    te0i[j] = ok ? tabd[T_TIEQ0*MT+ix] : 0.0;
    te1m[j] = ok ? tabd[T_TMEQ1*MT+ix] : 0.0;
    te1i[j] = ok ? tabd[T_TIEQ1*MT+ix] : 0.0;
    en0[j]  = ok ? tabd[T_ENT0 *MT+ix] : 0.0;
    en1[j]  = ok ? tabd[T_ENT1 *MT+ix] : 0.0;
    stpd[j] = ok ? tabd[T_STP  *MT+ix] : 0.0;
    i0v[j]  = ok ? tabd[T_I0   *MT+ix] : 0.0;
    i1v[j]  = ok ? tabd[T_I1   *MT+ix] : 0.0;
  }
  const double stp0 = stpd[0], stp1 = stpd[1];
  const double s2v = stpd[2];
  const double s12 = stpd[1]*stpd[2];

  // ---- loop-invariant DPP-scan window multipliers (log-space, preamble) ----
  {
  }
  double W1, W2, W4, W8, W5, W6;
  {
    double p = stpd[0]*stpd[1]*stpd[2];
    double lp = (p > 0.0) ? log(p) : -745.0;
    double LP = lp;
#pragma unroll
    for (int r = 0; r < 6; ++r) {
      double tq = __shfl_up(LP, 1 << r);
      if (lane >= (1 << r)) LP += tq;
    }
    double LPm1 = __shfl_up(LP, 1), LPm2 = __shfl_up(LP, 2),
           LPm4 = __shfl_up(LP, 4), LPm8 = __shfl_up(LP, 8);
    double LP31 = __shfl(LP, 31);
    int rs = lane & ~15;
    double LPrsm1 = __shfl(LP, rs > 0 ? rs - 1 : 0);
    int rl = lane & 15;
    W1 = (rl >= 1) ? exp(LP - LPm1) : 0.0;
    W2 = (rl >= 2) ? exp(LP - LPm2) : 0.0;
    W4 = (rl >= 4) ? exp(LP - LPm4) : 0.0;
    W8 = (rl >= 8) ? exp(LP - LPm8) : 0.0;
    W5 = (lane & 16) ? exp(LP - LPrsm1) : 0.0;   // rows 1,3
    W6 = (lane >= 32) ? exp(LP - LP31) : 0.0;    // rows 2,3
  }
  __syncthreads();

  // initial alpha (reweighted linear domain, fp64)
  double aM[3], aI[3];
  {
    int t0 = ldsT[0];
#pragma unroll
    for (int j = 0; j < 3; ++j) {
      aM[j] = i0v[j] * (double)ldsE[t0 + col[j]];
      aI[j] = i1v[j] * (double)ldsE[EI_REL + t0 + col[j]];
    }
  }
  int acc2i = 0;   // accumulated log2 of removed power-of-2 factors

  // prefetch emissions for t=1
  float fcm[3], fci[3];
  {
    int tf = ldsT[1];
#pragma unroll
    for (int j = 0; j < 3; ++j) {
      fcm[j] = ldsE[tf + col[j]];
      fci[j] = ldsE[EI_REL + tf + col[j]];
    }
  }

  for (int t = 1; t < LSEQ; ++t) {
    // prefetch next step's emissions (off critical path)
    int tfN = ldsT[(t + 1 < LSEQ) ? t + 1 : t];
    float fnm[3], fni[3];
#pragma unroll
    for (int j = 0; j < 3; ++j) {
      fnm[j] = ldsE[tfN + col[j]];
      fni[j] = ldsE[EI_REL + tfN + col[j]];
    }

    double ap0 = dpp_d<0x138, 0xF, true>(aM[2]);   // wave_shr:1, lane0 -> 0
    double ap[3] = {ap0, aM[0], aM[1]};
    double X[3], e0[3], e1[3];
#pragma unroll
    for (int j = 0; j < 3; ++j) {
      X[j]  = fma(ap[j], tmx[j],  aI[j]*tix[j]);   // feeds delete chain
      e0[j] = fma(ap[j], te0m[j], aI[j]*te0i[j]);  // direct -> (mp,0)
      e1[j] = fma(ap[j], te1m[j], aI[j]*te1i[j]);  // direct -> (mp,1)
    }
    // local composite, then 6-round DPP affine scan (64-lane inclusive)
    double x = fma(X[0], s12, fma(X[1], s2v, X[2]));
    double xs;
    xs = dpp_d<0x111, 0xF, true >(x); x = fma(xs, W1, x);  // row_shr:1
    xs = dpp_d<0x112, 0xF, true >(x); x = fma(xs, W2, x);  // row_shr:2
    xs = dpp_d<0x114, 0xF, true >(x); x = fma(xs, W4, x);  // row_shr:4
    xs = dpp_d<0x118, 0xF, true >(x); x = fma(xs, W8, x);  // row_shr:8
    xs = dpp_d<0x142, 0xA, false>(x); x = fma(xs, W5, x);  // bcast15 -> rows 1,3
    xs = dpp_d<0x143, 0xC, false>(x); x = fma(xs, W6, x);  // bcast31 -> rows 2,3
    double C0 = dpp_d<0x138, 0xF, true>(x);                // wave_shr:1
    double C1 = fma(C0, stp0, X[0]);
    double C2 = fma(C1, stp1, X[1]);
    double Cv[3] = {C0, C1, C2};
#pragma unroll
    for (int j = 0; j < 3; ++j) {
      double b0 = fma(en0[j], Cv[j], e0[j]);
      double b1 = fma(en1[j], Cv[j], e1[j]);
      aM[j] = b0 * (double)fcm[j];
      aI[j] = b1 * (double)fci[j];
    }
    // exact exponent-only renorm every 8 steps (target max ~= 2^500)
    if ((t & 7) == 0) {
      double m = fmax(fmax(fmax(aM[0],aM[1]), fmax(aM[2],aI[0])),
                      fmax(aI[1],aI[2]));
      m = fmax(m, dpp_d<0x111, 0xF, true >(m));
      m = fmax(m, dpp_d<0x112, 0xF, true >(m));
      m = fmax(m, dpp_d<0x114, 0xF, true >(m));
      m = fmax(m, dpp_d<0x118, 0xF, true >(m));
      m = fmax(m, dpp_d<0x142, 0xA, false>(m));
      m = fmax(m, dpp_d<0x143, 0xC, false>(m));
      int ehi = __builtin_amdgcn_readlane(__double2hiint(m), 63);
      int er  = (ehi >> 20) & 0x7FF;
      int dl  = er ? (1523 - er) : 0;     // multiply by 2^dl -> max ~ 2^500
      acc2i -= dl;
      double sc = __hiloint2double((1023 + dl) << 20, 0);
#pragma unroll
      for (int j = 0; j < 3; ++j) { aM[j] *= sc; aI[j] *= sc; }
    }
#pragma unroll
    for (int j = 0; j < 3; ++j) { fcm[j] = fnm[j]; fci[j] = fni[j]; }
  }

  // final: undo reweighting per state (log2 a = log2 a~ + B*log2e*mp + acc2)
  double l2[6];
#pragma unroll
  for (int j = 0; j < 3; ++j) {
    double vm = aM[j], vi = aI[j];
    double w = BETA * LOG2E * (double)(mp0 + j);
    l2[j]   = (vm > 0.0 ? log2(vm) + w : -1.0e300);
    l2[3+j] = (vi > 0.0 ? log2(vi) + w : -1.0e300);
  }
  double lm = l2[0];
#pragma unroll
  for (int j = 1; j < 6; ++j) lm = fmax(lm, l2[j]);
#pragma unroll
  for (int r = 0; r < 6; ++r) lm = fmax(lm, __shfl_xor(lm, 1 << r));
  lm = fmax(lm, -1.0e280);
  double s = 0.0;
#pragma unroll
  for (int j = 0; j < 6; ++j) s += exp2(l2[j] - lm);
#pragma unroll
  for (int r = 0; r < 6; ++r) s += __shfl_xor(s, 1 << r);
  if (lane == 0) {
    // correction: -255*BETA nats (e^{B t} reweight at t=255)
    out[n] = (float)(LN2*(lm + (double)acc2i + log2(s)) - 255.0*BETA);
  }
}

// ---------------------------------------------------------------- launch --
extern "C" void kernel_launch(void* const* d_in, const int* in_sizes, int n_in,
                              void* d_out, int out_size, void* d_ws, size_t ws_size,
                              hipStream_t stream) {
  const float* anc  = (const float*)d_in[0];
  const float* insq = (const float*)d_in[1];
  const float* rr   = (const float*)d_in[2];
  const float* uu   = (const float*)d_in[3];
  const float* data = (const float*)d_in[4];
  float* out = (float*)d_out;

  unsigned char* toks = (unsigned char*)d_ws;
  double* tabd = (double*)((char*)d_ws + TABD_OFF);
  float*  emf  = (float*) ((char*)d_ws + EMF_OFF);

  hipLaunchKernelGGL(prep_kernel, dim3(1),    dim3(256), 0, stream,
                     anc, insq, rr, uu, tabd, emf);
  hipLaunchKernelGGL(tok_kernel,  dim3(NSEQ), dim3(LSEQ), 0, stream, data, toks);
  hipLaunchKernelGGL(fwd_kernel,  dim3(NSEQ), dim3(64),  0, stream,
                     tabd, emf, toks, out);
}